// Round 1
// baseline (187.601 us; speedup 1.0000x reference)
//
#include <hip/hip_runtime.h>
#include <hip/hip_bf16.h>

// Joiner: logits[n,t,u,v] = sum_d tanh(enc[n,t,d]+dec[n,u,d]) * W[v,d] + b[v]
// N=8 T=200 U=100 D=512 V=500  -> GEMM M=160000, K=512, N=500 (padded 512)

#define NB 8
#define TT 200
#define UU 100
#define DD 512
#define VV 500
#define VP 512
#define BM 128
#define BK 32
#define KSTEPS 16          // 512/32
#define THREADS 512
#define LDA 40             // BK + 8 pad (ushort units, 80B row stride)
#define LDB 40
#define MROWS (NB*TT*UU)   // 160000
#define MBLOCKS (MROWS/BM) // 1250

typedef __attribute__((ext_vector_type(4))) float  f32x4;
typedef __attribute__((ext_vector_type(8))) short  s16x8;

__device__ __forceinline__ unsigned short f2bf(float f) {
    unsigned int u = __builtin_bit_cast(unsigned int, f);
    u = (u + 0x7FFFu + ((u >> 16) & 1u)) >> 16;   // round-to-nearest-even
    return (unsigned short)u;
}

__device__ __forceinline__ float fast_tanh(float x) {
    // tanh(x) = 1 - 2/(1+e^{2x}); handles both saturations via inf/0 of exp
    float e = __expf(2.0f * x);
    return 1.0f - 2.0f * __builtin_amdgcn_rcpf(e + 1.0f);
}

// ---- prep: W (500x512 f32) -> bf16, padded to 512 rows, tiled [kc][v][32] ----
__global__ void prep_w(const float* __restrict__ W, unsigned short* __restrict__ Wt) {
    int idx = blockIdx.x * 256 + threadIdx.x;   // 0 .. 512*512-1
    int k = idx & 511;
    int v = idx >> 9;
    float val = (v < VV) ? W[v * DD + k] : 0.0f;
    Wt[(k >> 5) * (VP * BK) + v * BK + (k & 31)] = f2bf(val);
}

__global__ __launch_bounds__(THREADS) void joiner_kernel(
    const float* __restrict__ enc, const float* __restrict__ dec,
    const unsigned short* __restrict__ Wt, const float* __restrict__ bias,
    float* __restrict__ out)
{
    __shared__ unsigned short lA[BM * LDA];     // 10240 B
    __shared__ unsigned short lB[VP * LDB];     // 40960 B
    __shared__ int rowE[BM];
    __shared__ int rowD[BM];

    const int tid = threadIdx.x;
    const int mb  = blockIdx.x;

    if (tid < BM) {
        int r   = mb * BM + tid;
        int n   = r / (TT * UU);
        int rem = r - n * (TT * UU);
        int t   = rem / UU;
        int u   = rem - t * UU;
        rowE[tid] = (n * TT + t) * DD;
        rowD[tid] = (n * UU + u) * DD;
    }
    __syncthreads();

    const int lane = tid & 63;
    const int w    = tid >> 6;
    const int wm   = w >> 2;        // 0..1  (64-row half)
    const int wn   = w & 3;         // 0..3  (128-col quarter)
    const int lr   = lane & 15;     // row (A) / col (B,C)
    const int lk   = lane >> 4;     // k-group of 8

    // staging indices: each thread produces 8 A elements
    const int srow = tid >> 2;          // 0..127
    const int sk   = (tid & 3) << 3;    // 0,8,16,24

    const int eoff = rowE[srow];
    const int doff = rowD[srow];

    f32x4 acc[4][8];
    #pragma unroll
    for (int m = 0; m < 4; ++m)
        #pragma unroll
        for (int f = 0; f < 8; ++f)
            acc[m][f] = (f32x4){0.f, 0.f, 0.f, 0.f};

    for (int kc = 0; kc < KSTEPS; ++kc) {
        // ---- stage A: activations tile 128x32 ----
        const float* ep = enc + eoff + kc * BK + sk;
        const float* dp = dec + doff + kc * BK + sk;
        f32x4 e0 = *(const f32x4*)(ep);
        f32x4 e1 = *(const f32x4*)(ep + 4);
        f32x4 d0 = *(const f32x4*)(dp);
        f32x4 d1 = *(const f32x4*)(dp + 4);
        s16x8 av;
        #pragma unroll
        for (int j = 0; j < 4; ++j) av[j]     = (short)f2bf(fast_tanh(e0[j] + d0[j]));
        #pragma unroll
        for (int j = 0; j < 4; ++j) av[4 + j] = (short)f2bf(fast_tanh(e1[j] + d1[j]));
        *(s16x8*)(&lA[srow * LDA + sk]) = av;

        // ---- stage B: W tile 512x32 (pre-tiled, coalesced 16B/lane) ----
        #pragma unroll
        for (int j = 0; j < 4; ++j) {
            int c  = j * THREADS + tid;          // 16B-chunk id, 0..2047
            int v  = c >> 2;
            int ch = c & 3;
            s16x8 wv = *(const s16x8*)(Wt + kc * (VP * BK) + c * 8);
            *(s16x8*)(&lB[v * LDB + ch * 8]) = wv;
        }
        __syncthreads();

        // ---- compute: 32 MFMAs per wave per K-step ----
        s16x8 a[4], b[8];
        #pragma unroll
        for (int m = 0; m < 4; ++m)
            a[m] = *(const s16x8*)(&lA[(wm * 64 + m * 16 + lr) * LDA + lk * 8]);
        #pragma unroll
        for (int f = 0; f < 8; ++f)
            b[f] = *(const s16x8*)(&lB[(wn * 128 + f * 16 + lr) * LDB + lk * 8]);
        #pragma unroll
        for (int m = 0; m < 4; ++m)
            #pragma unroll
            for (int f = 0; f < 8; ++f)
                acc[m][f] = __builtin_amdgcn_mfma_f32_16x16x32_bf16(a[m], b[f], acc[m][f], 0, 0, 0);
        __syncthreads();
    }

    // ---- epilogue: add bias, store fp32 ----
    const int r0 = mb * BM + wm * 64;
    #pragma unroll
    for (int f = 0; f < 8; ++f) {
        int v = wn * 128 + f * 16 + lr;
        if (v < VV) {
            float bv = bias[v];
            #pragma unroll
            for (int m = 0; m < 4; ++m) {
                int rbase = r0 + m * 16 + lk * 4;
                #pragma unroll
                for (int q = 0; q < 4; ++q)
                    out[(rbase + q) * VV + v] = acc[m][f][q] + bv;
            }
        }
    }
}

extern "C" void kernel_launch(void* const* d_in, const int* in_sizes, int n_in,
                              void* d_out, int out_size, void* d_ws, size_t ws_size,
                              hipStream_t stream) {
    const float* enc = (const float*)d_in[0];
    const float* dec = (const float*)d_in[1];
    const float* W   = (const float*)d_in[2];
    const float* b   = (const float*)d_in[3];
    float* out = (float*)d_out;
    unsigned short* Wt = (unsigned short*)d_ws;   // 512*512*2 = 512 KB

    prep_w<<<dim3((VP * DD) / 256), dim3(256), 0, stream>>>(W, Wt);
    joiner_kernel<<<dim3(MBLOCKS), dim3(THREADS), 0, stream>>>(enc, dec, Wt, b, out);
}

// Round 2
// 182.931 us; speedup vs baseline: 1.0255x; 1.0255x over previous
//
#include <hip/hip_runtime.h>
#include <hip/hip_bf16.h>

// Joiner: logits[n,t,u,v] = sum_d tanh(enc[n,t,d]+dec[n,u,d]) * W[v,d] + b[v]
// N=8 T=200 U=100 D=512 V=500  -> GEMM M=160000, K=512, N=500 (padded 512)
//
// R1 structure: BM=64 x BN=512, 256 threads (4 waves), BK=32.
//  - B fragments loaded directly global->VGPR from pre-tiled Wt (L2-resident,
//    each fragment load is a contiguous 1024B per wave -> fully coalesced).
//  - A (tanh activations) staged in double-buffered LDS, ONE barrier/K-step.
//  - enc/dec prefetched 2 steps ahead into registers (issue-early split).

#define NB 8
#define TT 200
#define UU 100
#define DD 512
#define VV 500
#define VP 512
#define BM 64
#define BK 32
#define KSTEPS 16          // 512/32
#define THREADS 256
#define LDA 40             // BK + 8 pad (ushort units, 80B row stride)
#define MROWS (NB*TT*UU)   // 160000
#define MBLOCKS (MROWS/BM) // 2500

typedef __attribute__((ext_vector_type(4))) float  f32x4;
typedef __attribute__((ext_vector_type(8))) short  s16x8;

__device__ __forceinline__ unsigned short f2bf(float f) {
    unsigned int u = __builtin_bit_cast(unsigned int, f);
    u = (u + 0x7FFFu + ((u >> 16) & 1u)) >> 16;   // round-to-nearest-even
    return (unsigned short)u;
}

__device__ __forceinline__ float fast_tanh(float x) {
    // tanh(x) = 1 - 2/(1+e^{2x}); saturations handled via exp inf/0
    float e = __expf(2.0f * x);
    return 1.0f - 2.0f * __builtin_amdgcn_rcpf(e + 1.0f);
}

// ---- prep: W (500x512 f32) -> bf16, padded to 512 rows, tiled [kc][v][32] ----
__global__ void prep_w(const float* __restrict__ W, unsigned short* __restrict__ Wt) {
    int idx = blockIdx.x * 256 + threadIdx.x;   // 0 .. 512*512-1
    int k = idx & 511;
    int v = idx >> 9;
    float val = (v < VV) ? W[v * DD + k] : 0.0f;
    Wt[(k >> 5) * (VP * BK) + v * BK + (k & 31)] = f2bf(val);
}

__global__ __launch_bounds__(THREADS, 2) void joiner_kernel(
    const float* __restrict__ enc, const float* __restrict__ dec,
    const unsigned short* __restrict__ Wt, const float* __restrict__ bias,
    float* __restrict__ out)
{
    __shared__ unsigned short lA[2][BM * LDA];   // 2 x 5120 B

    const int tid  = threadIdx.x;
    const int mb   = blockIdx.x;
    const int lane = tid & 63;
    const int wn   = tid >> 6;       // 0..3: 128-col quarter
    const int lr   = lane & 15;
    const int lk   = lane >> 4;

    // staging: each thread produces 8 activations of one row
    const int srow = tid >> 2;          // 0..63
    const int sk   = (tid & 3) << 3;    // 0,8,16,24

    {
    }
    int r   = mb * BM + srow;
    int n   = r / (TT * UU);
    int rem = r - n * (TT * UU);
    int t   = rem / UU;
    int u   = rem - t * UU;
    const float* ep = enc + (n * TT + t) * DD + sk;
    const float* dp = dec + (n * UU + u) * DD + sk;

    f32x4 e0, e1, d0, d1;

    // ---- stage kc=0 ----
    e0 = *(const f32x4*)(ep);     e1 = *(const f32x4*)(ep + 4);
    d0 = *(const f32x4*)(dp);     d1 = *(const f32x4*)(dp + 4);
    {
        s16x8 av;
        #pragma unroll
        for (int j = 0; j < 4; ++j) av[j]     = (short)f2bf(fast_tanh(e0[j] + d0[j]));
        #pragma unroll
        for (int j = 0; j < 4; ++j) av[4 + j] = (short)f2bf(fast_tanh(e1[j] + d1[j]));
        *(s16x8*)(&lA[0][srow * LDA + sk]) = av;
    }
    // ---- prefetch kc=1 into regs ----
    e0 = *(const f32x4*)(ep + BK);     e1 = *(const f32x4*)(ep + BK + 4);
    d0 = *(const f32x4*)(dp + BK);     d1 = *(const f32x4*)(dp + BK + 4);
    __syncthreads();

    f32x4 acc[4][8];
    #pragma unroll
    for (int m = 0; m < 4; ++m)
        #pragma unroll
        for (int f = 0; f < 8; ++f)
            acc[m][f] = (f32x4){0.f, 0.f, 0.f, 0.f};

    // per-thread B pointer into pre-tiled Wt: v = wn*128 + f*16 + lr, k = lk*8
    const unsigned short* wptr = Wt + (wn * 128 + lr) * BK + lk * 8;

    for (int kc = 0; kc < KSTEPS; ++kc) {
        // ---- B fragments: direct global->VGPR (L2-hit, coalesced 1KB/wave) ----
        s16x8 bF[8];
        #pragma unroll
        for (int f = 0; f < 8; ++f)
            bF[f] = *(const s16x8*)(wptr + kc * (VP * BK) + f * (16 * BK));

        // ---- A fragments from LDS (current buffer) ----
        s16x8 aF[4];
        #pragma unroll
        for (int m = 0; m < 4; ++m)
            aF[m] = *(const s16x8*)(&lA[kc & 1][(m * 16 + lr) * LDA + lk * 8]);

        // ---- stage next A tile (uses regs prefetched last iter), then
        //      issue global loads for the tile after that ----
        if (kc < KSTEPS - 1) {
            s16x8 av;
            #pragma unroll
            for (int j = 0; j < 4; ++j) av[j]     = (short)f2bf(fast_tanh(e0[j] + d0[j]));
            #pragma unroll
            for (int j = 0; j < 4; ++j) av[4 + j] = (short)f2bf(fast_tanh(e1[j] + d1[j]));
            *(s16x8*)(&lA[(kc + 1) & 1][srow * LDA + sk]) = av;
            if (kc < KSTEPS - 2) {
                const float* ep2 = ep + (kc + 2) * BK;
                const float* dp2 = dp + (kc + 2) * BK;
                e0 = *(const f32x4*)(ep2);     e1 = *(const f32x4*)(ep2 + 4);
                d0 = *(const f32x4*)(dp2);     d1 = *(const f32x4*)(dp2 + 4);
            }
        }

        // ---- 32 MFMAs ----
        #pragma unroll
        for (int m = 0; m < 4; ++m)
            #pragma unroll
            for (int f = 0; f < 8; ++f)
                acc[m][f] = __builtin_amdgcn_mfma_f32_16x16x32_bf16(aF[m], bF[f], acc[m][f], 0, 0, 0);

        __syncthreads();
    }

    // ---- epilogue: add bias, store fp32 ----
    const int r0 = mb * BM;
    #pragma unroll
    for (int f = 0; f < 8; ++f) {
        int v = wn * 128 + f * 16 + lr;
        if (v < VV) {
            float bv = bias[v];
            #pragma unroll
            for (int m = 0; m < 4; ++m) {
                int rbase = r0 + m * 16 + lk * 4;
                #pragma unroll
                for (int q = 0; q < 4; ++q)
                    out[(rbase + q) * VV + v] = acc[m][f][q] + bv;
            }
        }
    }
}

extern "C" void kernel_launch(void* const* d_in, const int* in_sizes, int n_in,
                              void* d_out, int out_size, void* d_ws, size_t ws_size,
                              hipStream_t stream) {
    const float* enc = (const float*)d_in[0];
    const float* dec = (const float*)d_in[1];
    const float* W   = (const float*)d_in[2];
    const float* b   = (const float*)d_in[3];
    float* out = (float*)d_out;
    unsigned short* Wt = (unsigned short*)d_ws;   // 512*512*2 = 512 KB

    prep_w<<<dim3((VP * DD) / 256), dim3(256), 0, stream>>>(W, Wt);
    joiner_kernel<<<dim3(MBLOCKS), dim3(THREADS), 0, stream>>>(enc, dec, Wt, b, out);
}

// Round 3
// 144.568 us; speedup vs baseline: 1.2977x; 1.2654x over previous
//
#include <hip/hip_runtime.h>
#include <hip/hip_bf16.h>

// Joiner: logits[n,t,u,v] = sum_d tanh(enc[n,t,d]+dec[n,u,d]) * W[v,d] + b[v]
// N=8 T=200 U=100 D=512 V=500  -> GEMM M=160000, K=512, N=500 (padded 512)
//
// R2: R1 K-loop (direct-B global->VGPR, A tanh-staged in dbuf LDS, 1 barrier/
// K-step) + STREAMING EPILOGUE: acc -> LDS 16-row chunks -> contiguous f32x4
// stores (fixes the 1.9 TB/s scattered-64B-write ceiling seen in R0/R1).

#define NB 8
#define TT 200
#define UU 100
#define DD 512
#define VV 500
#define VP 512
#define BM 64
#define BK 32
#define KSTEPS 16          // 512/32
#define THREADS 256
#define LDA 40             // BK + 8 pad (ushort units, 80B row stride)
#define MROWS (NB*TT*UU)   // 160000
#define MBLOCKS (MROWS/BM) // 2500

typedef __attribute__((ext_vector_type(4))) float  f32x4;
typedef __attribute__((ext_vector_type(8))) short  s16x8;

__device__ __forceinline__ unsigned short f2bf(float f) {
    unsigned int u = __builtin_bit_cast(unsigned int, f);
    u = (u + 0x7FFFu + ((u >> 16) & 1u)) >> 16;   // round-to-nearest-even
    return (unsigned short)u;
}

__device__ __forceinline__ float fast_tanh(float x) {
    float e = __expf(2.0f * x);
    return 1.0f - 2.0f * __builtin_amdgcn_rcpf(e + 1.0f);
}

// ---- prep: W (500x512 f32) -> bf16, padded to 512 rows, tiled [kc][v][32] ----
__global__ void prep_w(const float* __restrict__ W, unsigned short* __restrict__ Wt) {
    int idx = blockIdx.x * 256 + threadIdx.x;   // 0 .. 512*512-1
    int k = idx & 511;
    int v = idx >> 9;
    float val = (v < VV) ? W[v * DD + k] : 0.0f;
    Wt[(k >> 5) * (VP * BK) + v * BK + (k & 31)] = f2bf(val);
}

__global__ __launch_bounds__(THREADS, 2) void joiner_kernel(
    const float* __restrict__ enc, const float* __restrict__ dec,
    const unsigned short* __restrict__ Wt, const float* __restrict__ bias,
    float* __restrict__ out)
{
    // union: K-loop A buffers (10240 B) / epilogue chunk 16x500 f32 (32000 B)
    __shared__ __align__(16) char smem[32000];
    unsigned short* lA0 = (unsigned short*)smem;
    unsigned short* lA1 = (unsigned short*)(smem + BM * LDA * 2);

    const int tid  = threadIdx.x;
    const int mb   = blockIdx.x;
    const int lane = tid & 63;
    const int wn   = tid >> 6;       // 0..3: 128-col quarter
    const int lr   = lane & 15;
    const int lk   = lane >> 4;

    // staging: each thread produces 8 activations of one row
    const int srow = tid >> 2;          // 0..63
    const int sk   = (tid & 3) << 3;    // 0,8,16,24

    int r   = mb * BM + srow;
    int n   = r / (TT * UU);
    int rem = r - n * (TT * UU);
    int t   = rem / UU;
    int u   = rem - t * UU;
    const float* ep = enc + (n * TT + t) * DD + sk;
    const float* dp = dec + (n * UU + u) * DD + sk;

    f32x4 e0, e1, d0, d1;

    // ---- stage kc=0 ----
    e0 = *(const f32x4*)(ep);     e1 = *(const f32x4*)(ep + 4);
    d0 = *(const f32x4*)(dp);     d1 = *(const f32x4*)(dp + 4);
    {
        s16x8 av;
        #pragma unroll
        for (int j = 0; j < 4; ++j) av[j]     = (short)f2bf(fast_tanh(e0[j] + d0[j]));
        #pragma unroll
        for (int j = 0; j < 4; ++j) av[4 + j] = (short)f2bf(fast_tanh(e1[j] + d1[j]));
        *(s16x8*)(&lA0[srow * LDA + sk]) = av;
    }
    // ---- prefetch kc=1 into regs ----
    e0 = *(const f32x4*)(ep + BK);     e1 = *(const f32x4*)(ep + BK + 4);
    d0 = *(const f32x4*)(dp + BK);     d1 = *(const f32x4*)(dp + BK + 4);
    __syncthreads();

    f32x4 acc[4][8];
    #pragma unroll
    for (int m = 0; m < 4; ++m)
        #pragma unroll
        for (int f = 0; f < 8; ++f)
            acc[m][f] = (f32x4){0.f, 0.f, 0.f, 0.f};

    // per-thread B pointer into pre-tiled Wt: v = wn*128 + f*16 + lr, k = lk*8
    const unsigned short* wptr = Wt + (wn * 128 + lr) * BK + lk * 8;

    for (int kc = 0; kc < KSTEPS; ++kc) {
        unsigned short* lCur = (kc & 1) ? lA1 : lA0;
        unsigned short* lNxt = (kc & 1) ? lA0 : lA1;

        // ---- B fragments: direct global->VGPR (L2-hit, coalesced 1KB/wave) ----
        s16x8 bF[8];
        #pragma unroll
        for (int f = 0; f < 8; ++f)
            bF[f] = *(const s16x8*)(wptr + kc * (VP * BK) + f * (16 * BK));

        // ---- A fragments from LDS (current buffer) ----
        s16x8 aF[4];
        #pragma unroll
        for (int m = 0; m < 4; ++m)
            aF[m] = *(const s16x8*)(&lCur[(m * 16 + lr) * LDA + lk * 8]);

        // ---- stage next A tile, then prefetch the one after into regs ----
        if (kc < KSTEPS - 1) {
            s16x8 av;
            #pragma unroll
            for (int j = 0; j < 4; ++j) av[j]     = (short)f2bf(fast_tanh(e0[j] + d0[j]));
            #pragma unroll
            for (int j = 0; j < 4; ++j) av[4 + j] = (short)f2bf(fast_tanh(e1[j] + d1[j]));
            *(s16x8*)(&lNxt[srow * LDA + sk]) = av;
            if (kc < KSTEPS - 2) {
                const float* ep2 = ep + (kc + 2) * BK;
                const float* dp2 = dp + (kc + 2) * BK;
                e0 = *(const f32x4*)(ep2);     e1 = *(const f32x4*)(ep2 + 4);
                d0 = *(const f32x4*)(dp2);     d1 = *(const f32x4*)(dp2 + 4);
            }
        }

        // ---- 32 MFMAs ----
        __builtin_amdgcn_s_setprio(1);
        #pragma unroll
        for (int m = 0; m < 4; ++m)
            #pragma unroll
            for (int f = 0; f < 8; ++f)
                acc[m][f] = __builtin_amdgcn_mfma_f32_16x16x32_bf16(aF[m], bF[f], acc[m][f], 0, 0, 0);
        __builtin_amdgcn_s_setprio(0);

        __syncthreads();
    }

    // ---- epilogue: acc -> LDS 16-row chunks -> streaming f32x4 stores ----
    float bv[8];
    #pragma unroll
    for (int f = 0; f < 8; ++f) {
        int v = wn * 128 + f * 16 + lr;
        bv[f] = (v < VV) ? bias[v] : 0.0f;
    }

    float* lchunk = (float*)smem;                 // 16*500 f32 = 32000 B
    float* outbase = out + (long)mb * BM * VV;

    for (int m = 0; m < 4; ++m) {
        __syncthreads();   // previous chunk fully streamed / A-buffers done
        #pragma unroll
        for (int f = 0; f < 8; ++f) {
            int v = wn * 128 + f * 16 + lr;
            if (v < VV) {
                #pragma unroll
                for (int q = 0; q < 4; ++q)
                    lchunk[(lk * 4 + q) * VV + v] = acc[m][f][q] + bv[f];
            }
        }
        __syncthreads();
        // 16 rows x 500 f32 = 8000 contiguous floats = 2000 f32x4
        float* dst = outbase + m * 16 * VV;
        #pragma unroll
        for (int i = 0; i < 8; ++i) {
            int c = i * THREADS + tid;
            if (c < 2000)
                *(f32x4*)(dst + c * 4) = *(const f32x4*)(lchunk + c * 4);
        }
    }
}

extern "C" void kernel_launch(void* const* d_in, const int* in_sizes, int n_in,
                              void* d_out, int out_size, void* d_ws, size_t ws_size,
                              hipStream_t stream) {
    const float* enc = (const float*)d_in[0];
    const float* dec = (const float*)d_in[1];
    const float* W   = (const float*)d_in[2];
    const float* b   = (const float*)d_in[3];
    float* out = (float*)d_out;
    unsigned short* Wt = (unsigned short*)d_ws;   // 512*512*2 = 512 KB

    prep_w<<<dim3((VP * DD) / 256), dim3(256), 0, stream>>>(W, Wt);
    joiner_kernel<<<dim3(MBLOCKS), dim3(THREADS), 0, stream>>>(enc, dec, Wt, b, out);
}